// Round 7
// baseline (168.272 us; speedup 1.0000x reference)
//
#include <hip/hip_runtime.h>

#define N_NODES 100000
#define D 64
#define N_EDGES 1200000
#define NCB 391              // coarse buckets of 256 dst nodes: ceil(100000/256)
#define NBLK 128             // partition blocks
#define CHUNK ((N_EDGES + NBLK - 1) / NBLK)   // 9375 edges per block

// ---------- pass 1: per-block coarse histogram (dense writes) ----------
__global__ __launch_bounds__(256) void bin_hist(
    const int* __restrict__ eidx, int* __restrict__ hist)
{
    __shared__ int h[NCB];
    for (int i = threadIdx.x; i < NCB; i += 256) h[i] = 0;
    __syncthreads();
    const int blk = blockIdx.x;
    const int beg = blk * CHUNK;
    const int end = min(beg + CHUNK, N_EDGES);
    for (int e = beg + threadIdx.x; e < end; e += 256)
        atomicAdd(&h[eidx[N_EDGES + e] >> 8], 1);
    __syncthreads();
    for (int i = threadIdx.x; i < NCB; i += 256) hist[blk * NCB + i] = h[i];
}

// ---------- pass 2: bucket bases + per-(block,bucket) run starts ----------
__global__ __launch_bounds__(512) void bscan(
    const int* __restrict__ hist, int* __restrict__ boff,
    int* __restrict__ runstart, int* __restrict__ offs)
{
    __shared__ int tot[NCB];
    __shared__ int pfx[512];
    __shared__ int bo[NCB + 1];
    const int t = threadIdx.x;

    for (int i = t; i < NCB; i += 512) {
        int s = 0;
        #pragma unroll 4
        for (int blk = 0; blk < NBLK; ++blk) s += hist[blk * NCB + i];
        tot[i] = s;
    }
    __syncthreads();

    int v = (t < NCB) ? tot[t] : 0;
    pfx[t] = v;
    __syncthreads();
    for (int off = 1; off < 512; off <<= 1) {
        int x = (t >= off) ? pfx[t - off] : 0;
        __syncthreads();
        pfx[t] += x;
        __syncthreads();
    }
    if (t < NCB) bo[t] = pfx[t] - v;      // exclusive
    if (t == 0) { bo[NCB] = N_EDGES; offs[N_NODES] = N_EDGES; }
    __syncthreads();
    if (t < NCB + 1) boff[t] = bo[t];

    for (int i = t; i < NCB; i += 512) {
        int run = bo[i];
        #pragma unroll 4
        for (int blk = 0; blk < NBLK; ++blk) {
            runstart[blk * NCB + i] = run;
            run += hist[blk * NCB + i];
        }
    }
}

// ---------- pass 3: deterministic scatter into per-block sub-ranges ----------
__global__ __launch_bounds__(256) void bin_fill(
    const int* __restrict__ eidx, const int* __restrict__ runstart,
    unsigned int* __restrict__ pairs)
{
    __shared__ int lcur[NCB];
    const int blk = blockIdx.x;
    for (int i = threadIdx.x; i < NCB; i += 256) lcur[i] = runstart[blk * NCB + i];
    __syncthreads();
    const int beg = blk * CHUNK;
    const int end = min(beg + CHUNK, N_EDGES);
    for (int e = beg + threadIdx.x; e < end; e += 256) {
        int src = eidx[e];
        int dst = eidx[N_EDGES + e];
        int pos = atomicAdd(&lcur[dst >> 8], 1);
        pairs[pos] = ((unsigned int)src << 8) | (unsigned int)(dst & 255);
    }
}

// ---------- pass 4: fine sort within coarse bucket -> offs[] + csr[] ----------
// One block per 256-node bucket; output region [boff[b], boff[b+1]) contiguous.
__global__ __launch_bounds__(256) void fine_sort(
    const unsigned int* __restrict__ pairs,
    const int* __restrict__ boff,
    int* __restrict__ offs,
    int* __restrict__ csr)
{
    __shared__ int cnt[256];
    __shared__ int pfx[256];
    __shared__ int lcur[256];

    const int tid = threadIdx.x;
    const int b   = blockIdx.x;
    const int beg = boff[b];
    const int end = boff[b + 1];

    cnt[tid] = 0;
    __syncthreads();
    for (int j = beg + tid; j < end; j += 256)
        atomicAdd(&cnt[pairs[j] & 255], 1);
    __syncthreads();

    int v = cnt[tid];
    pfx[tid] = v;
    __syncthreads();
    for (int off = 1; off < 256; off <<= 1) {
        int x = (tid >= off) ? pfx[tid - off] : 0;
        __syncthreads();
        pfx[tid] += x;
        __syncthreads();
    }
    int ex = pfx[tid] - v;
    lcur[tid] = ex;
    int gn = b * 256 + tid;
    if (gn < N_NODES) offs[gn] = beg + ex;
    __syncthreads();

    for (int j = beg + tid; j < end; j += 256) {
        unsigned int p = pairs[j];
        int pos = beg + atomicAdd(&lcur[p & 255], 1);
        csr[pos] = (int)(p >> 8);
    }
}

// ---------- fused aggregate + linear: block = 64 nodes ----------
// Phase A: stage feat rows into X[.][0:64]; each wave aggregates 16 nodes'
// neighbor means into X[.][64:128] (register accumulate, LDS write).
// Phase B: 64x64 GEMM tile vs W (read from L2, not staged -> 33.8KB LDS,
// 4 blocks/CU = 16 waves/CU for gather latency hiding).
#define XS 132
__global__ __launch_bounds__(256) void sage_fused(
    const float* __restrict__ feat,
    const int* __restrict__ offs,
    const int* __restrict__ csr,
    const float* __restrict__ W,
    const float* __restrict__ bias,
    float* __restrict__ out)
{
    __shared__ float X[64 * XS];

    const int tid = threadIdx.x;
    const int nb  = blockIdx.x * 64;

    // stage self-features
    {
        const int sn = tid >> 4;
        const int kc = tid & 15;
        #pragma unroll
        for (int r = 0; r < 4; ++r) {
            int node = r * 16 + sn;
            int gn = nb + node;
            float4 f = make_float4(0.f, 0.f, 0.f, 0.f);
            if (gn < N_NODES)
                f = *(const float4*)(feat + (size_t)gn * 64 + kc * 4);
            *(float4*)(X + node * XS + kc * 4) = f;
        }
    }

    // aggregate neighbor means
    const int lane = tid & 63;
    const int wv   = tid >> 6;
    for (int i = 0; i < 16; ++i) {
        const int node = wv * 16 + i;
        const int n = nb + node;
        if (n >= N_NODES) break;
        const int beg = offs[n];
        const int end = offs[n + 1];
        float s = 0.0f;
        int e = beg;
        for (; e + 8 <= end; e += 8) {
            int i0 = csr[e], i1 = csr[e+1], i2 = csr[e+2], i3 = csr[e+3];
            int i4 = csr[e+4], i5 = csr[e+5], i6 = csr[e+6], i7 = csr[e+7];
            float a0 = feat[(size_t)i0 * D + lane];
            float a1 = feat[(size_t)i1 * D + lane];
            float a2 = feat[(size_t)i2 * D + lane];
            float a3 = feat[(size_t)i3 * D + lane];
            float a4 = feat[(size_t)i4 * D + lane];
            float a5 = feat[(size_t)i5 * D + lane];
            float a6 = feat[(size_t)i6 * D + lane];
            float a7 = feat[(size_t)i7 * D + lane];
            s += ((a0 + a1) + (a2 + a3)) + ((a4 + a5) + (a6 + a7));
        }
        if (e + 4 <= end) {
            int i0 = csr[e], i1 = csr[e+1], i2 = csr[e+2], i3 = csr[e+3];
            float a0 = feat[(size_t)i0 * D + lane];
            float a1 = feat[(size_t)i1 * D + lane];
            float a2 = feat[(size_t)i2 * D + lane];
            float a3 = feat[(size_t)i3 * D + lane];
            s += (a0 + a1) + (a2 + a3);
            e += 4;
        }
        for (; e < end; ++e) s += feat[(size_t)csr[e] * D + lane];
        float dg = (float)(end - beg);
        dg = dg > 1.0f ? dg : 1.0f;
        X[node * XS + 64 + lane] = s / dg;
    }
    __syncthreads();

    // GEMM tile: thread (ng,cg) does 4 nodes x 4 cols; W read from L2
    const int ng = tid >> 4;
    const int cg = tid & 15;

    const float4 b4 = *(const float4*)(bias + cg * 4);
    float acc[4][4];
    #pragma unroll
    for (int i = 0; i < 4; ++i) {
        acc[i][0] = b4.x; acc[i][1] = b4.y; acc[i][2] = b4.z; acc[i][3] = b4.w;
    }

    const float* x0p = X + (ng * 4 + 0) * XS;
    const float* x1p = X + (ng * 4 + 1) * XS;
    const float* x2p = X + (ng * 4 + 2) * XS;
    const float* x3p = X + (ng * 4 + 3) * XS;
    const float4* Wv = (const float4*)W;   // [k][16 float4]

    #pragma unroll 8
    for (int k = 0; k < 128; ++k) {
        float4 w4 = Wv[k * 16 + cg];
        float x0 = x0p[k];
        float x1 = x1p[k];
        float x2 = x2p[k];
        float x3 = x3p[k];
        acc[0][0] = fmaf(x0, w4.x, acc[0][0]);
        acc[0][1] = fmaf(x0, w4.y, acc[0][1]);
        acc[0][2] = fmaf(x0, w4.z, acc[0][2]);
        acc[0][3] = fmaf(x0, w4.w, acc[0][3]);
        acc[1][0] = fmaf(x1, w4.x, acc[1][0]);
        acc[1][1] = fmaf(x1, w4.y, acc[1][1]);
        acc[1][2] = fmaf(x1, w4.z, acc[1][2]);
        acc[1][3] = fmaf(x1, w4.w, acc[1][3]);
        acc[2][0] = fmaf(x2, w4.x, acc[2][0]);
        acc[2][1] = fmaf(x2, w4.y, acc[2][1]);
        acc[2][2] = fmaf(x2, w4.z, acc[2][2]);
        acc[2][3] = fmaf(x2, w4.w, acc[2][3]);
        acc[3][0] = fmaf(x3, w4.x, acc[3][0]);
        acc[3][1] = fmaf(x3, w4.y, acc[3][1]);
        acc[3][2] = fmaf(x3, w4.z, acc[3][2]);
        acc[3][3] = fmaf(x3, w4.w, acc[3][3]);
    }

    #pragma unroll
    for (int i = 0; i < 4; ++i) {
        int gn = nb + ng * 4 + i;
        if (gn < N_NODES) {
            float4 o = make_float4(acc[i][0], acc[i][1], acc[i][2], acc[i][3]);
            *(float4*)(out + (size_t)gn * 64 + cg * 4) = o;
        }
    }
}

extern "C" void kernel_launch(void* const* d_in, const int* in_sizes, int n_in,
                              void* d_out, int out_size, void* d_ws, size_t ws_size,
                              hipStream_t stream) {
    const float* feat = (const float*)d_in[0];
    const int*   eidx = (const int*)d_in[1];
    const float* W    = (const float*)d_in[2];
    const float* bias = (const float*)d_in[3];
    float* out = (float*)d_out;

    // workspace layout (ints) — every array fully written before read, no memset
    int* hist     = (int*)d_ws;                        // NBLK*NCB
    int* runstart = hist + NBLK * NCB;                 // NBLK*NCB
    int* boff     = runstart + NBLK * NCB;             // NCB + 1 (+pad)
    int* offs     = boff + NCB + 2;                    // N_NODES + 1
    unsigned int* pairs = (unsigned int*)(offs + N_NODES + 1);  // N_EDGES
    int* csr      = (int*)(pairs + N_EDGES);           // N_EDGES

    bin_hist<<<NBLK, 256, 0, stream>>>(eidx, hist);
    bscan<<<1, 512, 0, stream>>>(hist, boff, runstart, offs);
    bin_fill<<<NBLK, 256, 0, stream>>>(eidx, runstart, pairs);
    fine_sort<<<NCB, 256, 0, stream>>>(pairs, boff, offs, csr);
    sage_fused<<<(N_NODES + 63) / 64, 256, 0, stream>>>(feat, offs, csr, W, bias, out);
}

// Round 8
// 150.525 us; speedup vs baseline: 1.1179x; 1.1179x over previous
//
#include <hip/hip_runtime.h>

#define N_NODES 100000
#define D 64
#define N_EDGES 1200000
#define NCB 391              // coarse buckets of 256 dst nodes
#define NBLK 128             // partition blocks
#define CHUNK ((N_EDGES + NBLK - 1) / NBLK)   // 9375 edges per block

__device__ __forceinline__ unsigned short f2bf(float x) {
    unsigned int b = __float_as_uint(x);
    b += 0x7FFFu + ((b >> 16) & 1u);          // round-to-nearest-even
    return (unsigned short)(b >> 16);
}
__device__ __forceinline__ float bf2f(unsigned short u) {
    return __uint_as_float((unsigned int)u << 16);
}

// ---------- pass 1: per-block coarse histogram ----------
__global__ __launch_bounds__(256) void bin_hist(
    const int* __restrict__ eidx, int* __restrict__ hist)
{
    __shared__ int h[NCB];
    for (int i = threadIdx.x; i < NCB; i += 256) h[i] = 0;
    __syncthreads();
    const int blk = blockIdx.x;
    const int beg = blk * CHUNK;
    const int end = min(beg + CHUNK, N_EDGES);
    for (int e = beg + threadIdx.x; e < end; e += 256)
        atomicAdd(&h[eidx[N_EDGES + e] >> 8], 1);
    __syncthreads();
    for (int i = threadIdx.x; i < NCB; i += 256) hist[blk * NCB + i] = h[i];
}

// ---------- pass 2: bucket bases + per-(block,bucket) run starts ----------
__global__ __launch_bounds__(512) void bscan(
    const int* __restrict__ hist, int* __restrict__ boff,
    int* __restrict__ runstart, int* __restrict__ offs)
{
    __shared__ int tot[NCB];
    __shared__ int pfx[512];
    __shared__ int bo[NCB + 1];
    const int t = threadIdx.x;

    for (int i = t; i < NCB; i += 512) {
        int s = 0;
        #pragma unroll 4
        for (int blk = 0; blk < NBLK; ++blk) s += hist[blk * NCB + i];
        tot[i] = s;
    }
    __syncthreads();

    int v = (t < NCB) ? tot[t] : 0;
    pfx[t] = v;
    __syncthreads();
    for (int off = 1; off < 512; off <<= 1) {
        int x = (t >= off) ? pfx[t - off] : 0;
        __syncthreads();
        pfx[t] += x;
        __syncthreads();
    }
    if (t < NCB) bo[t] = pfx[t] - v;
    if (t == 0) { bo[NCB] = N_EDGES; offs[N_NODES] = N_EDGES; }
    __syncthreads();
    if (t < NCB + 1) boff[t] = bo[t];

    for (int i = t; i < NCB; i += 512) {
        int run = bo[i];
        #pragma unroll 4
        for (int blk = 0; blk < NBLK; ++blk) {
            runstart[blk * NCB + i] = run;
            run += hist[blk * NCB + i];
        }
    }
}

// ---------- pass 3: deterministic scatter into per-block sub-ranges ----------
__global__ __launch_bounds__(256) void bin_fill(
    const int* __restrict__ eidx, const int* __restrict__ runstart,
    unsigned int* __restrict__ pairs)
{
    __shared__ int lcur[NCB];
    const int blk = blockIdx.x;
    for (int i = threadIdx.x; i < NCB; i += 256) lcur[i] = runstart[blk * NCB + i];
    __syncthreads();
    const int beg = blk * CHUNK;
    const int end = min(beg + CHUNK, N_EDGES);
    for (int e = beg + threadIdx.x; e < end; e += 256) {
        int src = eidx[e];
        int dst = eidx[N_EDGES + e];
        int pos = atomicAdd(&lcur[dst >> 8], 1);
        pairs[pos] = ((unsigned int)src << 8) | (unsigned int)(dst & 255);
    }
}

// ---------- pass 4: fine sort within bucket -> offs[] + csr[] ----------
__global__ __launch_bounds__(256) void fine_sort(
    const unsigned int* __restrict__ pairs,
    const int* __restrict__ boff,
    int* __restrict__ offs,
    int* __restrict__ csr)
{
    __shared__ int cnt[256];
    __shared__ int pfx[256];
    __shared__ int lcur[256];

    const int tid = threadIdx.x;
    const int b   = blockIdx.x;
    const int beg = boff[b];
    const int end = boff[b + 1];

    cnt[tid] = 0;
    __syncthreads();
    for (int j = beg + tid; j < end; j += 256)
        atomicAdd(&cnt[pairs[j] & 255], 1);
    __syncthreads();

    int v = cnt[tid];
    pfx[tid] = v;
    __syncthreads();
    for (int off = 1; off < 256; off <<= 1) {
        int x = (tid >= off) ? pfx[tid - off] : 0;
        __syncthreads();
        pfx[tid] += x;
        __syncthreads();
    }
    int ex = pfx[tid] - v;
    lcur[tid] = ex;
    int gn = b * 256 + tid;
    if (gn < N_NODES) offs[gn] = beg + ex;
    __syncthreads();

    for (int j = beg + tid; j < end; j += 256) {
        unsigned int p = pairs[j];
        int pos = beg + atomicAdd(&lcur[p & 255], 1);
        csr[pos] = (int)(p >> 8);
    }
}

// ---------- feat f32 -> bf16 table (runs after fine_sort; fb overlaps pairs) ----------
__global__ __launch_bounds__(256) void to_bf16(
    const float* __restrict__ feat, ushort* __restrict__ fb)
{
    int i = blockIdx.x * 256 + threadIdx.x;     // one float4 per thread
    if (i >= N_NODES * D / 4) return;
    float4 v = ((const float4*)feat)[i];
    ushort4 o;
    o.x = f2bf(v.x); o.y = f2bf(v.y); o.z = f2bf(v.z); o.w = f2bf(v.w);
    ((ushort4*)fb)[i] = o;
}

// ---------- aggregation: wave per node, lane = dim; bf16 gathers ----------
__global__ __launch_bounds__(256) void aggregate(
    const ushort* __restrict__ fb,
    const int* __restrict__ offs,
    const int* __restrict__ csr,
    float* __restrict__ out)
{
    const int lane = threadIdx.x & 63;
    const int n = blockIdx.x * 4 + (threadIdx.x >> 6);
    if (n >= N_NODES) return;

    const int beg = offs[n];
    const int end = offs[n + 1];

    float s = 0.0f;
    int e = beg;
    for (; e + 8 <= end; e += 8) {
        int i0 = csr[e], i1 = csr[e+1], i2 = csr[e+2], i3 = csr[e+3];
        int i4 = csr[e+4], i5 = csr[e+5], i6 = csr[e+6], i7 = csr[e+7];
        float a0 = bf2f(fb[(size_t)i0 * D + lane]);
        float a1 = bf2f(fb[(size_t)i1 * D + lane]);
        float a2 = bf2f(fb[(size_t)i2 * D + lane]);
        float a3 = bf2f(fb[(size_t)i3 * D + lane]);
        float a4 = bf2f(fb[(size_t)i4 * D + lane]);
        float a5 = bf2f(fb[(size_t)i5 * D + lane]);
        float a6 = bf2f(fb[(size_t)i6 * D + lane]);
        float a7 = bf2f(fb[(size_t)i7 * D + lane]);
        s += ((a0 + a1) + (a2 + a3)) + ((a4 + a5) + (a6 + a7));
    }
    if (e + 4 <= end) {
        int i0 = csr[e], i1 = csr[e+1], i2 = csr[e+2], i3 = csr[e+3];
        float a0 = bf2f(fb[(size_t)i0 * D + lane]);
        float a1 = bf2f(fb[(size_t)i1 * D + lane]);
        float a2 = bf2f(fb[(size_t)i2 * D + lane]);
        float a3 = bf2f(fb[(size_t)i3 * D + lane]);
        s += (a0 + a1) + (a2 + a3);
        e += 4;
    }
    for (; e < end; ++e) s += bf2f(fb[(size_t)csr[e] * D + lane]);

    float dg = (float)(end - beg);
    dg = dg > 1.0f ? dg : 1.0f;
    out[(size_t)n * D + lane] = s / dg;
}

// ---------- linear: LDS X tile only; W via L1/L2 (4 blocks/CU) ----------
#define XS 132
__global__ __launch_bounds__(256) void sage_gemm(
    const float* __restrict__ feat,
    const float* __restrict__ W,
    const float* __restrict__ bias,
    float* __restrict__ out)
{
    __shared__ float X[64 * XS];

    const int tid = threadIdx.x;
    const int nb  = blockIdx.x * 64;

    {
        const int sn = tid >> 4;
        const int kc = tid & 15;
        #pragma unroll
        for (int r = 0; r < 4; ++r) {
            int node = r * 16 + sn;
            int gn = nb + node;
            float4 f = make_float4(0.f, 0.f, 0.f, 0.f);
            float4 m = make_float4(0.f, 0.f, 0.f, 0.f);
            if (gn < N_NODES) {
                f = *(const float4*)(feat + (size_t)gn * 64 + kc * 4);
                m = *(const float4*)(out  + (size_t)gn * 64 + kc * 4);
            }
            *(float4*)(X + node * XS + kc * 4)      = f;
            *(float4*)(X + node * XS + 64 + kc * 4) = m;
        }
    }
    __syncthreads();

    const int ng = tid >> 4;
    const int cg = tid & 15;

    const float4 b4 = *(const float4*)(bias + cg * 4);
    float acc[4][4];
    #pragma unroll
    for (int i = 0; i < 4; ++i) {
        acc[i][0] = b4.x; acc[i][1] = b4.y; acc[i][2] = b4.z; acc[i][3] = b4.w;
    }

    const float* x0p = X + (ng * 4 + 0) * XS;
    const float* x1p = X + (ng * 4 + 1) * XS;
    const float* x2p = X + (ng * 4 + 2) * XS;
    const float* x3p = X + (ng * 4 + 3) * XS;
    const float4* Wv = (const float4*)W;

    #pragma unroll 8
    for (int k = 0; k < 128; ++k) {
        float4 w4 = Wv[k * 16 + cg];
        float x0 = x0p[k];
        float x1 = x1p[k];
        float x2 = x2p[k];
        float x3 = x3p[k];
        acc[0][0] = fmaf(x0, w4.x, acc[0][0]);
        acc[0][1] = fmaf(x0, w4.y, acc[0][1]);
        acc[0][2] = fmaf(x0, w4.z, acc[0][2]);
        acc[0][3] = fmaf(x0, w4.w, acc[0][3]);
        acc[1][0] = fmaf(x1, w4.x, acc[1][0]);
        acc[1][1] = fmaf(x1, w4.y, acc[1][1]);
        acc[1][2] = fmaf(x1, w4.z, acc[1][2]);
        acc[1][3] = fmaf(x1, w4.w, acc[1][3]);
        acc[2][0] = fmaf(x2, w4.x, acc[2][0]);
        acc[2][1] = fmaf(x2, w4.y, acc[2][1]);
        acc[2][2] = fmaf(x2, w4.z, acc[2][2]);
        acc[2][3] = fmaf(x2, w4.w, acc[2][3]);
        acc[3][0] = fmaf(x3, w4.x, acc[3][0]);
        acc[3][1] = fmaf(x3, w4.y, acc[3][1]);
        acc[3][2] = fmaf(x3, w4.z, acc[3][2]);
        acc[3][3] = fmaf(x3, w4.w, acc[3][3]);
    }

    #pragma unroll
    for (int i = 0; i < 4; ++i) {
        int gn = nb + ng * 4 + i;
        if (gn < N_NODES) {
            float4 o = make_float4(acc[i][0], acc[i][1], acc[i][2], acc[i][3]);
            *(float4*)(out + (size_t)gn * 64 + cg * 4) = o;
        }
    }
}

extern "C" void kernel_launch(void* const* d_in, const int* in_sizes, int n_in,
                              void* d_out, int out_size, void* d_ws, size_t ws_size,
                              hipStream_t stream) {
    const float* feat = (const float*)d_in[0];
    const int*   eidx = (const int*)d_in[1];
    const float* W    = (const float*)d_in[2];
    const float* bias = (const float*)d_in[3];
    float* out = (float*)d_out;

    // ws layout (ints). fb overlaps pairs (pairs dead after fine_sort;
    // to_bf16 launches after fine_sort). Total ~18.4 MB.
    int* hist     = (int*)d_ws;                        // NBLK*NCB
    int* runstart = hist + NBLK * NCB;                 // NBLK*NCB
    int* boff     = runstart + NBLK * NCB;             // NCB + 2
    int* offs     = boff + NCB + 2;                    // N_NODES + 1
    int* csr      = offs + N_NODES + 1;                // N_EDGES
    unsigned int* pairs = (unsigned int*)(csr + N_EDGES);  // union w/ fb
    ushort* fb    = (ushort*)pairs;                    // N_NODES*D bf16

    bin_hist<<<NBLK, 256, 0, stream>>>(eidx, hist);
    bscan<<<1, 512, 0, stream>>>(hist, boff, runstart, offs);
    bin_fill<<<NBLK, 256, 0, stream>>>(eidx, runstart, pairs);
    fine_sort<<<NCB, 256, 0, stream>>>(pairs, boff, offs, csr);
    to_bf16<<<(N_NODES * D / 4 + 255) / 256, 256, 0, stream>>>(feat, fb);
    aggregate<<<(N_NODES + 3) / 4, 256, 0, stream>>>(fb, offs, csr, out);
    sage_gemm<<<(N_NODES + 63) / 64, 256, 0, stream>>>(feat, W, bias, out);
}

// Round 9
// 141.321 us; speedup vs baseline: 1.1907x; 1.0651x over previous
//
#include <hip/hip_runtime.h>

#define N_NODES 100000
#define D 64
#define N_EDGES 1200000
#define NCB 391              // coarse buckets of 256 dst nodes
#define NBLK 256             // partition blocks
#define CHUNK ((N_EDGES + NBLK - 1) / NBLK)   // 4688 edges per block

__device__ __forceinline__ unsigned short f2bf(float x) {
    unsigned int b = __float_as_uint(x);
    b += 0x7FFFu + ((b >> 16) & 1u);          // round-to-nearest-even
    return (unsigned short)(b >> 16);
}
__device__ __forceinline__ float bf2f(unsigned short u) {
    return __uint_as_float((unsigned int)u << 16);
}

// ---------- pass 1: per-block coarse histogram ----------
__global__ __launch_bounds__(256) void bin_hist(
    const int* __restrict__ eidx, int* __restrict__ hist)
{
    __shared__ int h[NCB];
    for (int i = threadIdx.x; i < NCB; i += 256) h[i] = 0;
    __syncthreads();
    const int blk = blockIdx.x;
    const int beg = blk * CHUNK;
    const int end = min(beg + CHUNK, N_EDGES);
    for (int e = beg + threadIdx.x; e < end; e += 256)
        atomicAdd(&h[eidx[N_EDGES + e] >> 8], 1);
    __syncthreads();
    for (int i = threadIdx.x; i < NCB; i += 256) hist[blk * NCB + i] = h[i];
}

// ---------- pass 2: bucket bases + per-(block,bucket) run starts ----------
__global__ __launch_bounds__(512) void bscan(
    const int* __restrict__ hist, int* __restrict__ boff,
    int* __restrict__ runstart, int* __restrict__ offs)
{
    __shared__ int tot[NCB];
    __shared__ int pfx[512];
    __shared__ int bo[NCB + 1];
    const int t = threadIdx.x;

    for (int i = t; i < NCB; i += 512) {
        int s = 0;
        #pragma unroll 4
        for (int blk = 0; blk < NBLK; ++blk) s += hist[blk * NCB + i];
        tot[i] = s;
    }
    __syncthreads();

    int v = (t < NCB) ? tot[t] : 0;
    pfx[t] = v;
    __syncthreads();
    for (int off = 1; off < 512; off <<= 1) {
        int x = (t >= off) ? pfx[t - off] : 0;
        __syncthreads();
        pfx[t] += x;
        __syncthreads();
    }
    if (t < NCB) bo[t] = pfx[t] - v;
    if (t == 0) { bo[NCB] = N_EDGES; offs[N_NODES] = N_EDGES; }
    __syncthreads();
    if (t < NCB + 1) boff[t] = bo[t];

    for (int i = t; i < NCB; i += 512) {
        int run = bo[i];
        #pragma unroll 4
        for (int blk = 0; blk < NBLK; ++blk) {
            runstart[blk * NCB + i] = run;
            run += hist[blk * NCB + i];
        }
    }
}

// ---------- pass 3: deterministic scatter into per-block sub-ranges ----------
__global__ __launch_bounds__(256) void bin_fill(
    const int* __restrict__ eidx, const int* __restrict__ runstart,
    unsigned int* __restrict__ pairs)
{
    __shared__ int lcur[NCB];
    const int blk = blockIdx.x;
    for (int i = threadIdx.x; i < NCB; i += 256) lcur[i] = runstart[blk * NCB + i];
    __syncthreads();
    const int beg = blk * CHUNK;
    const int end = min(beg + CHUNK, N_EDGES);
    for (int e = beg + threadIdx.x; e < end; e += 256) {
        int src = eidx[e];
        int dst = eidx[N_EDGES + e];
        int pos = atomicAdd(&lcur[dst >> 8], 1);
        pairs[pos] = ((unsigned int)src << 8) | (unsigned int)(dst & 255);
    }
}

// ---------- pass 4: fine sort within bucket -> offs[] + csr[] ----------
__global__ __launch_bounds__(256) void fine_sort(
    const unsigned int* __restrict__ pairs,
    const int* __restrict__ boff,
    int* __restrict__ offs,
    int* __restrict__ csr)
{
    __shared__ int cnt[256];
    __shared__ int pfx[256];
    __shared__ int lcur[256];

    const int tid = threadIdx.x;
    const int b   = blockIdx.x;
    const int beg = boff[b];
    const int end = boff[b + 1];

    cnt[tid] = 0;
    __syncthreads();
    for (int j = beg + tid; j < end; j += 256)
        atomicAdd(&cnt[pairs[j] & 255], 1);
    __syncthreads();

    int v = cnt[tid];
    pfx[tid] = v;
    __syncthreads();
    for (int off = 1; off < 256; off <<= 1) {
        int x = (tid >= off) ? pfx[tid - off] : 0;
        __syncthreads();
        pfx[tid] += x;
        __syncthreads();
    }
    int ex = pfx[tid] - v;
    lcur[tid] = ex;
    int gn = b * 256 + tid;
    if (gn < N_NODES) offs[gn] = beg + ex;
    __syncthreads();

    for (int j = beg + tid; j < end; j += 256) {
        unsigned int p = pairs[j];
        int pos = beg + atomicAdd(&lcur[p & 255], 1);
        csr[pos] = (int)(p >> 8);
    }
}

// ---------- feat f32 -> bf16 table (runs after fine_sort; fb overlaps pairs) ----------
__global__ __launch_bounds__(256) void to_bf16(
    const float* __restrict__ feat, ushort* __restrict__ fb)
{
    int i = blockIdx.x * 256 + threadIdx.x;     // one float4 per thread
    if (i >= N_NODES * D / 4) return;
    float4 v = ((const float4*)feat)[i];
    ushort4 o;
    o.x = f2bf(v.x); o.y = f2bf(v.y); o.z = f2bf(v.z); o.w = f2bf(v.w);
    ((ushort4*)fb)[i] = o;
}

// ---------- aggregation: 4 nodes per wave, 16 lanes per node ----------
// Lane l of quarter q handles dims 4l..4l+3 of node (wave*4+q): ushort4
// gathers (128B/row/quarter), 4 independent edge loops x 4-deep unroll
// -> up to 16 outstanding gathers per wave.
__global__ __launch_bounds__(256) void aggregate(
    const ushort* __restrict__ fb,
    const int* __restrict__ offs,
    const int* __restrict__ csr,
    float* __restrict__ out)
{
    const int tid = threadIdx.x;
    const int l   = tid & 15;                 // lane within quarter
    const int n   = blockIdx.x * 16 + (tid >> 4);   // 16 nodes per block
    if (n >= N_NODES) return;

    const int beg = offs[n];
    const int end = offs[n + 1];
    const ushort4* f4 = (const ushort4*)fb;

    float s0 = 0.f, s1 = 0.f, s2 = 0.f, s3 = 0.f;
    int e = beg;
    for (; e + 4 <= end; e += 4) {
        int i0 = csr[e], i1 = csr[e+1], i2 = csr[e+2], i3 = csr[e+3];
        ushort4 v0 = f4[(size_t)i0 * 16 + l];
        ushort4 v1 = f4[(size_t)i1 * 16 + l];
        ushort4 v2 = f4[(size_t)i2 * 16 + l];
        ushort4 v3 = f4[(size_t)i3 * 16 + l];
        s0 += (bf2f(v0.x) + bf2f(v1.x)) + (bf2f(v2.x) + bf2f(v3.x));
        s1 += (bf2f(v0.y) + bf2f(v1.y)) + (bf2f(v2.y) + bf2f(v3.y));
        s2 += (bf2f(v0.z) + bf2f(v1.z)) + (bf2f(v2.z) + bf2f(v3.z));
        s3 += (bf2f(v0.w) + bf2f(v1.w)) + (bf2f(v2.w) + bf2f(v3.w));
    }
    for (; e < end; ++e) {
        ushort4 v = f4[(size_t)csr[e] * 16 + l];
        s0 += bf2f(v.x); s1 += bf2f(v.y); s2 += bf2f(v.z); s3 += bf2f(v.w);
    }

    float dg = (float)(end - beg);
    dg = dg > 1.0f ? dg : 1.0f;
    float inv = 1.0f / dg;
    float4 o = make_float4(s0 * inv, s1 * inv, s2 * inv, s3 * inv);
    *(float4*)(out + (size_t)n * 64 + l * 4) = o;
}

// ---------- linear: LDS X tile; self-feat from bf16 table; W via L1/L2 ----------
#define XS 132
__global__ __launch_bounds__(256) void sage_gemm(
    const ushort* __restrict__ fb,
    const float* __restrict__ W,
    const float* __restrict__ bias,
    float* __restrict__ out)
{
    __shared__ float X[64 * XS];

    const int tid = threadIdx.x;
    const int nb  = blockIdx.x * 64;

    {
        const int sn = tid >> 4;
        const int kc = tid & 15;
        #pragma unroll
        for (int r = 0; r < 4; ++r) {
            int node = r * 16 + sn;
            int gn = nb + node;
            float4 f = make_float4(0.f, 0.f, 0.f, 0.f);
            float4 m = make_float4(0.f, 0.f, 0.f, 0.f);
            if (gn < N_NODES) {
                ushort4 a = *(const ushort4*)(fb + (size_t)gn * 64 + kc * 4);
                f = make_float4(bf2f(a.x), bf2f(a.y), bf2f(a.z), bf2f(a.w));
                m = *(const float4*)(out + (size_t)gn * 64 + kc * 4);
            }
            *(float4*)(X + node * XS + kc * 4)      = f;
            *(float4*)(X + node * XS + 64 + kc * 4) = m;
        }
    }
    __syncthreads();

    const int ng = tid >> 4;
    const int cg = tid & 15;

    const float4 b4 = *(const float4*)(bias + cg * 4);
    float acc[4][4];
    #pragma unroll
    for (int i = 0; i < 4; ++i) {
        acc[i][0] = b4.x; acc[i][1] = b4.y; acc[i][2] = b4.z; acc[i][3] = b4.w;
    }

    const float* x0p = X + (ng * 4 + 0) * XS;
    const float* x1p = X + (ng * 4 + 1) * XS;
    const float* x2p = X + (ng * 4 + 2) * XS;
    const float* x3p = X + (ng * 4 + 3) * XS;
    const float4* Wv = (const float4*)W;

    #pragma unroll 8
    for (int k = 0; k < 128; ++k) {
        float4 w4 = Wv[k * 16 + cg];
        float x0 = x0p[k];
        float x1 = x1p[k];
        float x2 = x2p[k];
        float x3 = x3p[k];
        acc[0][0] = fmaf(x0, w4.x, acc[0][0]);
        acc[0][1] = fmaf(x0, w4.y, acc[0][1]);
        acc[0][2] = fmaf(x0, w4.z, acc[0][2]);
        acc[0][3] = fmaf(x0, w4.w, acc[0][3]);
        acc[1][0] = fmaf(x1, w4.x, acc[1][0]);
        acc[1][1] = fmaf(x1, w4.y, acc[1][1]);
        acc[1][2] = fmaf(x1, w4.z, acc[1][2]);
        acc[1][3] = fmaf(x1, w4.w, acc[1][3]);
        acc[2][0] = fmaf(x2, w4.x, acc[2][0]);
        acc[2][1] = fmaf(x2, w4.y, acc[2][1]);
        acc[2][2] = fmaf(x2, w4.z, acc[2][2]);
        acc[2][3] = fmaf(x2, w4.w, acc[2][3]);
        acc[3][0] = fmaf(x3, w4.x, acc[3][0]);
        acc[3][1] = fmaf(x3, w4.y, acc[3][1]);
        acc[3][2] = fmaf(x3, w4.z, acc[3][2]);
        acc[3][3] = fmaf(x3, w4.w, acc[3][3]);
    }

    #pragma unroll
    for (int i = 0; i < 4; ++i) {
        int gn = nb + ng * 4 + i;
        if (gn < N_NODES) {
            float4 o = make_float4(acc[i][0], acc[i][1], acc[i][2], acc[i][3]);
            *(float4*)(out + (size_t)gn * 64 + cg * 4) = o;
        }
    }
}

extern "C" void kernel_launch(void* const* d_in, const int* in_sizes, int n_in,
                              void* d_out, int out_size, void* d_ws, size_t ws_size,
                              hipStream_t stream) {
    const float* feat = (const float*)d_in[0];
    const int*   eidx = (const int*)d_in[1];
    const float* W    = (const float*)d_in[2];
    const float* bias = (const float*)d_in[3];
    float* out = (float*)d_out;

    // ws layout (ints). fb overlaps pairs (pairs dead after fine_sort).
    int* hist     = (int*)d_ws;                        // NBLK*NCB
    int* runstart = hist + NBLK * NCB;                 // NBLK*NCB
    int* boff     = runstart + NBLK * NCB;             // NCB + 2
    int* offs     = boff + NCB + 2;                    // N_NODES + 1
    int* csr      = offs + N_NODES + 1;                // N_EDGES
    unsigned int* pairs = (unsigned int*)(csr + N_EDGES);  // union w/ fb
    ushort* fb    = (ushort*)pairs;                    // N_NODES*D bf16

    bin_hist<<<NBLK, 256, 0, stream>>>(eidx, hist);
    bscan<<<1, 512, 0, stream>>>(hist, boff, runstart, offs);
    bin_fill<<<NBLK, 256, 0, stream>>>(eidx, runstart, pairs);
    fine_sort<<<NCB, 256, 0, stream>>>(pairs, boff, offs, csr);
    to_bf16<<<(N_NODES * D / 4 + 255) / 256, 256, 0, stream>>>(feat, fb);
    aggregate<<<(N_NODES + 15) / 16, 256, 0, stream>>>(fb, offs, csr, out);
    sage_gemm<<<(N_NODES + 63) / 64, 256, 0, stream>>>(fb, W, bias, out);
}

// Round 10
// 119.341 us; speedup vs baseline: 1.4100x; 1.1842x over previous
//
#include <hip/hip_runtime.h>

#define N_NODES 100000
#define D 64
#define N_EDGES 1200000
#define NCB 391              // coarse buckets of 256 dst nodes
#define NBLK 256             // partition blocks
#define CHUNK ((N_EDGES + NBLK - 1) / NBLK)   // 4688 edges per block

typedef __attribute__((ext_vector_type(8))) short short8v;   // 8 bf16
typedef __attribute__((ext_vector_type(4))) float f32x4;

__device__ __forceinline__ unsigned short f2bf(float x) {
    unsigned int b = __float_as_uint(x);
    b += 0x7FFFu + ((b >> 16) & 1u);          // round-to-nearest-even
    return (unsigned short)(b >> 16);
}
__device__ __forceinline__ float bf2f(unsigned short u) {
    return __uint_as_float((unsigned int)u << 16);
}

// ---------- pass 1: per-block coarse histogram ----------
__global__ __launch_bounds__(256) void bin_hist(
    const int* __restrict__ eidx, int* __restrict__ hist)
{
    __shared__ int h[NCB];
    for (int i = threadIdx.x; i < NCB; i += 256) h[i] = 0;
    __syncthreads();
    const int blk = blockIdx.x;
    const int beg = blk * CHUNK;
    const int end = min(beg + CHUNK, N_EDGES);
    for (int e = beg + threadIdx.x; e < end; e += 256)
        atomicAdd(&h[eidx[N_EDGES + e] >> 8], 1);
    __syncthreads();
    for (int i = threadIdx.x; i < NCB; i += 256) hist[blk * NCB + i] = h[i];
}

// ---------- pass 2: bucket bases + run starts; also builds W frag table ----------
// wb layout: [t][c4][lane][j] = bf16( W[32t + (lane>>4)*8 + j][16*c4 + (lane&15)] )
__global__ __launch_bounds__(512) void bscan(
    const int* __restrict__ hist, int* __restrict__ boff,
    int* __restrict__ runstart, int* __restrict__ offs,
    const float* __restrict__ W, ushort* __restrict__ wb)
{
    __shared__ int tot[NCB];
    __shared__ int pfx[512];
    __shared__ int bo[NCB + 1];
    const int t = threadIdx.x;

    // W fragment table (independent of the scan)
    for (int g = t; g < 8192; g += 512) {
        int j  = g & 7;
        int l  = (g >> 3) & 63;
        int c4 = (g >> 9) & 3;
        int tt = g >> 11;
        int k   = 32 * tt + ((l >> 4) << 3) + j;
        int col = 16 * c4 + (l & 15);
        wb[g] = f2bf(W[k * 64 + col]);
    }

    for (int i = t; i < NCB; i += 512) {
        int s = 0;
        #pragma unroll 4
        for (int blk = 0; blk < NBLK; ++blk) s += hist[blk * NCB + i];
        tot[i] = s;
    }
    __syncthreads();

    int v = (t < NCB) ? tot[t] : 0;
    pfx[t] = v;
    __syncthreads();
    for (int off = 1; off < 512; off <<= 1) {
        int x = (t >= off) ? pfx[t - off] : 0;
        __syncthreads();
        pfx[t] += x;
        __syncthreads();
    }
    if (t < NCB) bo[t] = pfx[t] - v;
    if (t == 0) { bo[NCB] = N_EDGES; offs[N_NODES] = N_EDGES; }
    __syncthreads();
    if (t < NCB + 1) boff[t] = bo[t];

    for (int i = t; i < NCB; i += 512) {
        int run = bo[i];
        #pragma unroll 4
        for (int blk = 0; blk < NBLK; ++blk) {
            runstart[blk * NCB + i] = run;
            run += hist[blk * NCB + i];
        }
    }
}

// ---------- pass 3: deterministic scatter into per-block sub-ranges ----------
__global__ __launch_bounds__(256) void bin_fill(
    const int* __restrict__ eidx, const int* __restrict__ runstart,
    unsigned int* __restrict__ pairs)
{
    __shared__ int lcur[NCB];
    const int blk = blockIdx.x;
    for (int i = threadIdx.x; i < NCB; i += 256) lcur[i] = runstart[blk * NCB + i];
    __syncthreads();
    const int beg = blk * CHUNK;
    const int end = min(beg + CHUNK, N_EDGES);
    for (int e = beg + threadIdx.x; e < end; e += 256) {
        int src = eidx[e];
        int dst = eidx[N_EDGES + e];
        int pos = atomicAdd(&lcur[dst >> 8], 1);
        pairs[pos] = ((unsigned int)src << 8) | (unsigned int)(dst & 255);
    }
}

// ---------- pass 4: fine sort within bucket -> offs[] + csr[] ----------
__global__ __launch_bounds__(256) void fine_sort(
    const unsigned int* __restrict__ pairs,
    const int* __restrict__ boff,
    int* __restrict__ offs,
    int* __restrict__ csr)
{
    __shared__ int cnt[256];
    __shared__ int pfx[256];
    __shared__ int lcur[256];

    const int tid = threadIdx.x;
    const int b   = blockIdx.x;
    const int beg = boff[b];
    const int end = boff[b + 1];

    cnt[tid] = 0;
    __syncthreads();
    for (int j = beg + tid; j < end; j += 256)
        atomicAdd(&cnt[pairs[j] & 255], 1);
    __syncthreads();

    int v = cnt[tid];
    pfx[tid] = v;
    __syncthreads();
    for (int off = 1; off < 256; off <<= 1) {
        int x = (tid >= off) ? pfx[tid - off] : 0;
        __syncthreads();
        pfx[tid] += x;
        __syncthreads();
    }
    int ex = pfx[tid] - v;
    lcur[tid] = ex;
    int gn = b * 256 + tid;
    if (gn < N_NODES) offs[gn] = beg + ex;
    __syncthreads();

    for (int j = beg + tid; j < end; j += 256) {
        unsigned int p = pairs[j];
        int pos = beg + atomicAdd(&lcur[p & 255], 1);
        csr[pos] = (int)(p >> 8);
    }
}

// ---------- feat f32 -> bf16 table (after fine_sort; fb overlaps pairs) ----------
__global__ __launch_bounds__(256) void to_bf16(
    const float* __restrict__ feat, ushort* __restrict__ fb)
{
    int i = blockIdx.x * 256 + threadIdx.x;     // one float4 per thread
    if (i >= N_NODES * D / 4) return;
    float4 v = ((const float4*)feat)[i];
    ushort4 o;
    o.x = f2bf(v.x); o.y = f2bf(v.y); o.z = f2bf(v.z); o.w = f2bf(v.w);
    ((ushort4*)fb)[i] = o;
}

// ---------- aggregation: 4 nodes per wave, 16 lanes per node ----------
// Writes the MEAN as 64 bf16 into the first 128 bytes of out row n.
__global__ __launch_bounds__(256) void aggregate(
    const ushort* __restrict__ fb,
    const int* __restrict__ offs,
    const int* __restrict__ csr,
    float* out)
{
    const int tid = threadIdx.x;
    const int l   = tid & 15;                 // lane within quarter
    const int n   = blockIdx.x * 16 + (tid >> 4);   // 16 nodes per block
    if (n >= N_NODES) return;

    const int beg = offs[n];
    const int end = offs[n + 1];
    const ushort4* f4 = (const ushort4*)fb;

    float s0 = 0.f, s1 = 0.f, s2 = 0.f, s3 = 0.f;
    int e = beg;
    for (; e + 4 <= end; e += 4) {
        int i0 = csr[e], i1 = csr[e+1], i2 = csr[e+2], i3 = csr[e+3];
        ushort4 v0 = f4[(size_t)i0 * 16 + l];
        ushort4 v1 = f4[(size_t)i1 * 16 + l];
        ushort4 v2 = f4[(size_t)i2 * 16 + l];
        ushort4 v3 = f4[(size_t)i3 * 16 + l];
        s0 += (bf2f(v0.x) + bf2f(v1.x)) + (bf2f(v2.x) + bf2f(v3.x));
        s1 += (bf2f(v0.y) + bf2f(v1.y)) + (bf2f(v2.y) + bf2f(v3.y));
        s2 += (bf2f(v0.z) + bf2f(v1.z)) + (bf2f(v2.z) + bf2f(v3.z));
        s3 += (bf2f(v0.w) + bf2f(v1.w)) + (bf2f(v2.w) + bf2f(v3.w));
    }
    for (; e < end; ++e) {
        ushort4 v = f4[(size_t)csr[e] * 16 + l];
        s0 += bf2f(v.x); s1 += bf2f(v.y); s2 += bf2f(v.z); s3 += bf2f(v.w);
    }

    float dg = (float)(end - beg);
    dg = dg > 1.0f ? dg : 1.0f;
    float inv = 1.0f / dg;
    ushort4 o;
    o.x = f2bf(s0 * inv); o.y = f2bf(s1 * inv);
    o.z = f2bf(s2 * inv); o.w = f2bf(s3 * inv);
    // mean bf16 at ushort offset n*128 + l*4 (first 128B of out row n)
    *(ushort4*)((ushort*)out + (size_t)n * 128 + l * 4) = o;
}

// ---------- MFMA GEMM: wave = 16 nodes, K=128, no LDS ----------
// A-frags: lane l holds row n0+(l&15), k = 32t + (l>>4)*8 + j (16B loads).
// B-frags: preformatted wb table. C/D: col = l&15 (+16*c4), row = (l>>4)*4+r.
// Reads bf16 means from out rows (first 128B), then overwrites rows with f32.
__global__ __launch_bounds__(256) void mfma_gemm(
    const ushort* __restrict__ fb,
    const ushort* __restrict__ wb,
    const float* __restrict__ bias,
    float* out)
{
    const int lane = threadIdx.x & 63;
    const int wv   = threadIdx.x >> 6;
    const int n0   = blockIdx.x * 64 + wv * 16;
    if (n0 >= N_NODES) return;

    const int kg = lane >> 4;      // k-group 0..3
    const int cl = lane & 15;      // A-row / D-col within tile

    // B fragments: 16 x 16B coalesced loads
    short8v bfrag[4][4];
    #pragma unroll
    for (int t = 0; t < 4; ++t)
        #pragma unroll
        for (int c4 = 0; c4 < 4; ++c4)
            bfrag[t][c4] = *(const short8v*)(wb + (size_t)(((t * 4 + c4) * 64) + lane) * 8);

    // accumulators init with bias (bias depends on col only)
    f32x4 acc[4];
    #pragma unroll
    for (int c4 = 0; c4 < 4; ++c4) {
        float bv = bias[c4 * 16 + cl];
        acc[c4] = (f32x4){bv, bv, bv, bv};
    }

    const int row = n0 + cl;
    const ushort* frow = fb + (size_t)row * 64;
    const ushort* mrow = (const ushort*)out + (size_t)row * 128;  // bf16 means

    short8v afrag[4];
    afrag[0] = *(const short8v*)(frow + kg * 8);
    afrag[1] = *(const short8v*)(frow + 32 + kg * 8);
    afrag[2] = *(const short8v*)(mrow + kg * 8);
    afrag[3] = *(const short8v*)(mrow + 32 + kg * 8);

    #pragma unroll
    for (int t = 0; t < 4; ++t)
        #pragma unroll
        for (int c4 = 0; c4 < 4; ++c4)
            acc[c4] = __builtin_amdgcn_mfma_f32_16x16x32_bf16(
                afrag[t], bfrag[t][c4], acc[c4], 0, 0, 0);

    // store: lane writes rows n0 + kg*4 + r, cols c4*16 + cl
    #pragma unroll
    for (int c4 = 0; c4 < 4; ++c4)
        #pragma unroll
        for (int r = 0; r < 4; ++r)
            out[(size_t)(n0 + kg * 4 + r) * 64 + c4 * 16 + cl] = acc[c4][r];
}

extern "C" void kernel_launch(void* const* d_in, const int* in_sizes, int n_in,
                              void* d_out, int out_size, void* d_ws, size_t ws_size,
                              hipStream_t stream) {
    const float* feat = (const float*)d_in[0];
    const int*   eidx = (const int*)d_in[1];
    const float* W    = (const float*)d_in[2];
    const float* bias = (const float*)d_in[3];
    float* out = (float*)d_out;

    // ws layout (ints). fb overlaps pairs (pairs dead after fine_sort).
    int* hist     = (int*)d_ws;                        // NBLK*NCB
    int* runstart = hist + NBLK * NCB;                 // NBLK*NCB
    int* boff     = runstart + NBLK * NCB;             // NCB + 2
    int* offs     = boff + NCB + 2;                    // N_NODES + 1
    int* csr      = offs + N_NODES + 1;                // N_EDGES
    ushort* wb    = (ushort*)(csr + N_EDGES);          // 8192 bf16 W frag table
    unsigned int* pairs = (unsigned int*)(wb + 8192);  // union w/ fb
    ushort* fb    = (ushort*)pairs;                    // N_NODES*D bf16

    bin_hist<<<NBLK, 256, 0, stream>>>(eidx, hist);
    bscan<<<1, 512, 0, stream>>>(hist, boff, runstart, offs, W, wb);
    bin_fill<<<NBLK, 256, 0, stream>>>(eidx, runstart, pairs);
    fine_sort<<<NCB, 256, 0, stream>>>(pairs, boff, offs, csr);
    to_bf16<<<(N_NODES * D / 4 + 255) / 256, 256, 0, stream>>>(feat, fb);
    aggregate<<<(N_NODES + 15) / 16, 256, 0, stream>>>(fb, offs, csr, out);
    mfma_gemm<<<(N_NODES + 63) / 64, 256, 0, stream>>>(fb, wb, bias, out);
}

// Round 11
// 112.331 us; speedup vs baseline: 1.4980x; 1.0624x over previous
//
#include <hip/hip_runtime.h>

#define N_NODES 100000
#define D 64
#define N_EDGES 1200000
#define NCB 391              // coarse buckets of 256 dst nodes
#define NBLK 256             // partition blocks
#define CHUNK ((N_EDGES + NBLK - 1) / NBLK)   // 4688 edges per block

typedef __attribute__((ext_vector_type(8))) short short8v;   // 8 bf16
typedef __attribute__((ext_vector_type(4))) float f32x4;

__device__ __forceinline__ unsigned short f2bf(float x) {
    unsigned int b = __float_as_uint(x);
    b += 0x7FFFu + ((b >> 16) & 1u);          // round-to-nearest-even
    return (unsigned short)(b >> 16);
}
__device__ __forceinline__ float bf2f(unsigned short u) {
    return __uint_as_float((unsigned int)u << 16);
}

// ---------- pass 1: per-block coarse histogram + feat->bf16 table ----------
__global__ __launch_bounds__(256) void bin_hist(
    const int* __restrict__ eidx, int* __restrict__ hist,
    const float* __restrict__ feat, ushort* __restrict__ fb)
{
    __shared__ int h[NCB];
    for (int i = threadIdx.x; i < NCB; i += 256) h[i] = 0;
    __syncthreads();
    const int blk = blockIdx.x;
    const int beg = blk * CHUNK;
    const int end = min(beg + CHUNK, N_EDGES);
    for (int e = beg + threadIdx.x; e < end; e += 256)
        atomicAdd(&h[eidx[N_EDGES + e] >> 8], 1);
    __syncthreads();
    for (int i = threadIdx.x; i < NCB; i += 256) hist[blk * NCB + i] = h[i];

    // folded bf16 conversion: one float4 -> ushort4 per iter
    const int total4 = N_NODES * D / 4;       // 1.6M elements / 4
    for (int i = blk * 256 + threadIdx.x; i < total4; i += NBLK * 256) {
        float4 v = ((const float4*)feat)[i];
        ushort4 o;
        o.x = f2bf(v.x); o.y = f2bf(v.y); o.z = f2bf(v.z); o.w = f2bf(v.w);
        ((ushort4*)fb)[i] = o;
    }
}

// ---------- pass 2: bucket bases + run starts; also builds W frag table ----------
// wb layout: [t][c4][lane][j] = bf16( W[32t + (lane>>4)*8 + j][16*c4 + (lane&15)] )
__global__ __launch_bounds__(512) void bscan(
    const int* __restrict__ hist, int* __restrict__ boff,
    int* __restrict__ runstart, int* __restrict__ offs,
    const float* __restrict__ W, ushort* __restrict__ wb)
{
    __shared__ int tot[NCB];
    __shared__ int pfx[512];
    __shared__ int bo[NCB + 1];
    const int t = threadIdx.x;

    for (int g = t; g < 8192; g += 512) {
        int j  = g & 7;
        int l  = (g >> 3) & 63;
        int c4 = (g >> 9) & 3;
        int tt = g >> 11;
        int k   = 32 * tt + ((l >> 4) << 3) + j;
        int col = 16 * c4 + (l & 15);
        wb[g] = f2bf(W[k * 64 + col]);
    }

    for (int i = t; i < NCB; i += 512) {
        int s = 0;
        #pragma unroll 4
        for (int blk = 0; blk < NBLK; ++blk) s += hist[blk * NCB + i];
        tot[i] = s;
    }
    __syncthreads();

    int v = (t < NCB) ? tot[t] : 0;
    pfx[t] = v;
    __syncthreads();
    for (int off = 1; off < 512; off <<= 1) {
        int x = (t >= off) ? pfx[t - off] : 0;
        __syncthreads();
        pfx[t] += x;
        __syncthreads();
    }
    if (t < NCB) bo[t] = pfx[t] - v;
    if (t == 0) { bo[NCB] = N_EDGES; offs[N_NODES] = N_EDGES; }
    __syncthreads();
    if (t < NCB + 1) boff[t] = bo[t];

    for (int i = t; i < NCB; i += 512) {
        int run = bo[i];
        #pragma unroll 4
        for (int blk = 0; blk < NBLK; ++blk) {
            runstart[blk * NCB + i] = run;
            run += hist[blk * NCB + i];
        }
    }
}

// ---------- pass 3: deterministic scatter into per-block sub-ranges ----------
__global__ __launch_bounds__(256) void bin_fill(
    const int* __restrict__ eidx, const int* __restrict__ runstart,
    unsigned int* __restrict__ pairs)
{
    __shared__ int lcur[NCB];
    const int blk = blockIdx.x;
    for (int i = threadIdx.x; i < NCB; i += 256) lcur[i] = runstart[blk * NCB + i];
    __syncthreads();
    const int beg = blk * CHUNK;
    const int end = min(beg + CHUNK, N_EDGES);
    for (int e = beg + threadIdx.x; e < end; e += 256) {
        int src = eidx[e];
        int dst = eidx[N_EDGES + e];
        int pos = atomicAdd(&lcur[dst >> 8], 1);
        pairs[pos] = ((unsigned int)src << 8) | (unsigned int)(dst & 255);
    }
}

// ---------- pass 4: fine sort within bucket -> offs[] + csr[] ----------
__global__ __launch_bounds__(256) void fine_sort(
    const unsigned int* __restrict__ pairs,
    const int* __restrict__ boff,
    int* __restrict__ offs,
    int* __restrict__ csr)
{
    __shared__ int cnt[256];
    __shared__ int pfx[256];
    __shared__ int lcur[256];

    const int tid = threadIdx.x;
    const int b   = blockIdx.x;
    const int beg = boff[b];
    const int end = boff[b + 1];

    cnt[tid] = 0;
    __syncthreads();
    for (int j = beg + tid; j < end; j += 256)
        atomicAdd(&cnt[pairs[j] & 255], 1);
    __syncthreads();

    int v = cnt[tid];
    pfx[tid] = v;
    __syncthreads();
    for (int off = 1; off < 256; off <<= 1) {
        int x = (tid >= off) ? pfx[tid - off] : 0;
        __syncthreads();
        pfx[tid] += x;
        __syncthreads();
    }
    int ex = pfx[tid] - v;
    lcur[tid] = ex;
    int gn = b * 256 + tid;
    if (gn < N_NODES) offs[gn] = beg + ex;
    __syncthreads();

    for (int j = beg + tid; j < end; j += 256) {
        unsigned int p = pairs[j];
        int pos = beg + atomicAdd(&lcur[p & 255], 1);
        csr[pos] = (int)(p >> 8);
    }
}

// ---------- fused aggregate + MFMA linear: block = 16 nodes ----------
// Phase A (gather): quarter-wave (16 lanes) per node, ushort4 gathers,
// 8 edges in flight; mean (bf16) -> LDS. wb -> LDS copy overlaps.
// Phase B (MFMA): wave wv computes column quadrant wv for all 16 nodes:
// A-frags from fb (self) + LDS means; B-frags from LDS wb; 4 MFMAs.
#define MROW 72   // means row stride in ushorts (144B: 16B-aligned, 2-way banks)
__global__ __launch_bounds__(256) void agg_gemm(
    const ushort* __restrict__ fb,
    const int* __restrict__ offs,
    const int* __restrict__ csr,
    const ushort* __restrict__ wb,
    const float* __restrict__ bias,
    float* __restrict__ out)
{
    __shared__ __attribute__((aligned(16))) ushort wbl[8192];
    __shared__ __attribute__((aligned(16))) ushort means[16 * MROW];

    const int tid = threadIdx.x;
    const int n0  = blockIdx.x * 16;

    // wb -> LDS (independent of gather; covered by the same barrier)
    {
        const short8v* src = (const short8v*)wb;
        short8v* dst = (short8v*)wbl;
        #pragma unroll
        for (int r = 0; r < 4; ++r) dst[r * 256 + tid] = src[r * 256 + tid];
    }

    // ----- Phase A: gather -----
    const int l    = tid & 15;
    const int node = tid >> 4;
    const int n    = n0 + node;

    const int beg = offs[n];
    const int end = offs[n + 1];
    const ushort4* f4 = (const ushort4*)fb;

    float s0 = 0.f, s1 = 0.f, s2 = 0.f, s3 = 0.f;
    int e = beg;
    for (; e + 8 <= end; e += 8) {
        int i0 = csr[e],   i1 = csr[e+1], i2 = csr[e+2], i3 = csr[e+3];
        int i4 = csr[e+4], i5 = csr[e+5], i6 = csr[e+6], i7 = csr[e+7];
        ushort4 v0 = f4[(size_t)i0 * 16 + l];
        ushort4 v1 = f4[(size_t)i1 * 16 + l];
        ushort4 v2 = f4[(size_t)i2 * 16 + l];
        ushort4 v3 = f4[(size_t)i3 * 16 + l];
        ushort4 v4 = f4[(size_t)i4 * 16 + l];
        ushort4 v5 = f4[(size_t)i5 * 16 + l];
        ushort4 v6 = f4[(size_t)i6 * 16 + l];
        ushort4 v7 = f4[(size_t)i7 * 16 + l];
        s0 += ((bf2f(v0.x) + bf2f(v1.x)) + (bf2f(v2.x) + bf2f(v3.x)))
            + ((bf2f(v4.x) + bf2f(v5.x)) + (bf2f(v6.x) + bf2f(v7.x)));
        s1 += ((bf2f(v0.y) + bf2f(v1.y)) + (bf2f(v2.y) + bf2f(v3.y)))
            + ((bf2f(v4.y) + bf2f(v5.y)) + (bf2f(v6.y) + bf2f(v7.y)));
        s2 += ((bf2f(v0.z) + bf2f(v1.z)) + (bf2f(v2.z) + bf2f(v3.z)))
            + ((bf2f(v4.z) + bf2f(v5.z)) + (bf2f(v6.z) + bf2f(v7.z)));
        s3 += ((bf2f(v0.w) + bf2f(v1.w)) + (bf2f(v2.w) + bf2f(v3.w)))
            + ((bf2f(v4.w) + bf2f(v5.w)) + (bf2f(v6.w) + bf2f(v7.w)));
    }
    for (; e + 4 <= end; e += 4) {
        int i0 = csr[e], i1 = csr[e+1], i2 = csr[e+2], i3 = csr[e+3];
        ushort4 v0 = f4[(size_t)i0 * 16 + l];
        ushort4 v1 = f4[(size_t)i1 * 16 + l];
        ushort4 v2 = f4[(size_t)i2 * 16 + l];
        ushort4 v3 = f4[(size_t)i3 * 16 + l];
        s0 += (bf2f(v0.x) + bf2f(v1.x)) + (bf2f(v2.x) + bf2f(v3.x));
        s1 += (bf2f(v0.y) + bf2f(v1.y)) + (bf2f(v2.y) + bf2f(v3.y));
        s2 += (bf2f(v0.z) + bf2f(v1.z)) + (bf2f(v2.z) + bf2f(v3.z));
        s3 += (bf2f(v0.w) + bf2f(v1.w)) + (bf2f(v2.w) + bf2f(v3.w));
    }
    for (; e < end; ++e) {
        ushort4 v = f4[(size_t)csr[e] * 16 + l];
        s0 += bf2f(v.x); s1 += bf2f(v.y); s2 += bf2f(v.z); s3 += bf2f(v.w);
    }

    float dg = (float)(end - beg);
    dg = dg > 1.0f ? dg : 1.0f;
    float inv = 1.0f / dg;
    {
        ushort4 o;
        o.x = f2bf(s0 * inv); o.y = f2bf(s1 * inv);
        o.z = f2bf(s2 * inv); o.w = f2bf(s3 * inv);
        *(ushort4*)(means + node * MROW + l * 4) = o;
    }
    __syncthreads();

    // ----- Phase B: MFMA, wave wv = column quadrant wv -----
    const int lane = tid & 63;
    const int wv   = tid >> 6;
    const int kg   = lane >> 4;    // k-group 0..3
    const int cl   = lane & 15;    // A-row (node) / D-col within tile

    const ushort* frow = fb + (size_t)(n0 + cl) * 64;
    short8v a0 = *(const short8v*)(frow + kg * 8);
    short8v a1 = *(const short8v*)(frow + 32 + kg * 8);
    short8v a2 = *(const short8v*)(means + cl * MROW + kg * 8);
    short8v a3 = *(const short8v*)(means + cl * MROW + 32 + kg * 8);

    float bv = bias[wv * 16 + cl];
    f32x4 acc = (f32x4){bv, bv, bv, bv};

    acc = __builtin_amdgcn_mfma_f32_16x16x32_bf16(
        a0, *(const short8v*)(wbl + (size_t)((0 * 4 + wv) * 64 + lane) * 8), acc, 0, 0, 0);
    acc = __builtin_amdgcn_mfma_f32_16x16x32_bf16(
        a1, *(const short8v*)(wbl + (size_t)((1 * 4 + wv) * 64 + lane) * 8), acc, 0, 0, 0);
    acc = __builtin_amdgcn_mfma_f32_16x16x32_bf16(
        a2, *(const short8v*)(wbl + (size_t)((2 * 4 + wv) * 64 + lane) * 8), acc, 0, 0, 0);
    acc = __builtin_amdgcn_mfma_f32_16x16x32_bf16(
        a3, *(const short8v*)(wbl + (size_t)((3 * 4 + wv) * 64 + lane) * 8), acc, 0, 0, 0);

    // store: lane writes rows n0 + kg*4 + r, cols wv*16 + cl
    #pragma unroll
    for (int r = 0; r < 4; ++r)
        out[(size_t)(n0 + kg * 4 + r) * 64 + wv * 16 + cl] = acc[r];
}

extern "C" void kernel_launch(void* const* d_in, const int* in_sizes, int n_in,
                              void* d_out, int out_size, void* d_ws, size_t ws_size,
                              hipStream_t stream) {
    const float* feat = (const float*)d_in[0];
    const int*   eidx = (const int*)d_in[1];
    const float* W    = (const float*)d_in[2];
    const float* bias = (const float*)d_in[3];
    float* out = (float*)d_out;

    // ws layout (~14 MB; ws is ~268 MB). fb no longer overlaps pairs.
    int* hist     = (int*)d_ws;                        // NBLK*NCB
    int* runstart = hist + NBLK * NCB;                 // NBLK*NCB
    int* boff     = runstart + NBLK * NCB;             // NCB + 2
    int* offs     = boff + NCB + 2;                    // N_NODES + 1
    int* csr      = offs + N_NODES + 1;                // N_EDGES
    ushort* wb    = (ushort*)(csr + N_EDGES);          // 8192 bf16 W frag table
    unsigned int* pairs = (unsigned int*)(wb + 8192);  // N_EDGES
    ushort* fb    = (ushort*)(pairs + N_EDGES);        // N_NODES*D bf16

    bin_hist<<<NBLK, 256, 0, stream>>>(eidx, hist, feat, fb);
    bscan<<<1, 512, 0, stream>>>(hist, boff, runstart, offs, W, wb);
    bin_fill<<<NBLK, 256, 0, stream>>>(eidx, runstart, pairs);
    fine_sort<<<NCB, 256, 0, stream>>>(pairs, boff, offs, csr);
    agg_gemm<<<N_NODES / 16, 256, 0, stream>>>(fb, offs, csr, wb, bias, out);
}

// Round 12
// 97.330 us; speedup vs baseline: 1.7289x; 1.1541x over previous
//
#include <hip/hip_runtime.h>

#define N_NODES 100000
#define D 64
#define N_EDGES 1200000
#define NCB 391              // coarse buckets of 256 dst nodes
#define NBLK 256             // partition blocks (== rstart/bin_fill threads)
#define PAD 16               // pad per-bucket total counters to 64B lines
#define CHUNK ((N_EDGES + NBLK - 1) / NBLK)   // 4688 edges per block

typedef __attribute__((ext_vector_type(8))) short short8v;          // 8 bf16 (MFMA frag)
typedef __attribute__((ext_vector_type(8))) unsigned short ushort8v; // 8 bf16 raw
typedef __attribute__((ext_vector_type(4))) float f32x4;

__device__ __forceinline__ unsigned short f2bf(float x) {
    unsigned int b = __float_as_uint(x);
    b += 0x7FFFu + ((b >> 16) & 1u);          // round-to-nearest-even
    return (unsigned short)(b >> 16);
}
__device__ __forceinline__ float bf2f(unsigned short u) {
    return __uint_as_float((unsigned int)u << 16);
}

// ---------- pass 1: per-block coarse histogram + bucket totals + fb + wb ----------
__global__ __launch_bounds__(256) void bin_hist(
    const int* __restrict__ eidx, int* __restrict__ hist, int* __restrict__ totP,
    const float* __restrict__ feat, ushort* __restrict__ fb,
    const float* __restrict__ W, ushort* __restrict__ wb)
{
    __shared__ int h[NCB];
    for (int i = threadIdx.x; i < NCB; i += 256) h[i] = 0;
    __syncthreads();
    const int blk = blockIdx.x;

    // W fragment table: wb[t][c4][lane][j] = bf16(W[32t+(lane>>4)*8+j][16c4+(lane&15)])
    if (blk < 32) {
        int g  = blk * 256 + threadIdx.x;     // 0..8191
        int j  = g & 7;
        int l  = (g >> 3) & 63;
        int c4 = (g >> 9) & 3;
        int tt = g >> 11;
        int k   = 32 * tt + ((l >> 4) << 3) + j;
        int col = 16 * c4 + (l & 15);
        wb[g] = f2bf(W[k * 64 + col]);
    }

    const int beg = blk * CHUNK;
    const int end = min(beg + CHUNK, N_EDGES);
    for (int e = beg + threadIdx.x; e < end; e += 256)
        atomicAdd(&h[eidx[N_EDGES + e] >> 8], 1);

    // folded bf16 conversion of the feature table
    const int total4 = N_NODES * D / 4;
    for (int i = blk * 256 + threadIdx.x; i < total4; i += NBLK * 256) {
        float4 v = ((const float4*)feat)[i];
        ushort4 o;
        o.x = f2bf(v.x); o.y = f2bf(v.y); o.z = f2bf(v.z); o.w = f2bf(v.w);
        ((ushort4*)fb)[i] = o;
    }

    __syncthreads();
    for (int i = threadIdx.x; i < NCB; i += 256) {
        int v = h[i];
        hist[blk * NCB + i] = v;
        if (v) atomicAdd(&totP[i * PAD], v);
    }
}

// ---------- pass 2: per-bucket base + per-(block,bucket) run starts (parallel) ----------
// block i: bo_i = sum_{j<i} totP[j]; column scan of hist[.][i] over 256 blocks.
__global__ __launch_bounds__(256) void rstart(
    const int* __restrict__ totP, const int* __restrict__ hist,
    int* __restrict__ boff, int* __restrict__ runstart, int* __restrict__ offs)
{
    __shared__ int red[256];
    __shared__ int pfx[256];
    __shared__ int bo_s;

    const int tid = threadIdx.x;
    const int i   = blockIdx.x;

    int p = 0;
    for (int j = tid; j < i; j += 256) p += totP[j * PAD];
    red[tid] = p;
    __syncthreads();
    for (int off = 128; off > 0; off >>= 1) {
        if (tid < off) red[tid] += red[tid + off];
        __syncthreads();
    }
    if (tid == 0) {
        bo_s = red[0];
        boff[i] = red[0];
        if (i == 0) { boff[NCB] = N_EDGES; offs[N_NODES] = N_EDGES; }
    }
    __syncthreads();

    // exclusive scan over the 256 partition blocks (thread tid = block tid)
    int v = hist[tid * NCB + i];
    pfx[tid] = v;
    __syncthreads();
    for (int off = 1; off < 256; off <<= 1) {
        int x = (tid >= off) ? pfx[tid - off] : 0;
        __syncthreads();
        pfx[tid] += x;
        __syncthreads();
    }
    runstart[tid * NCB + i] = bo_s + pfx[tid] - v;
}

// ---------- pass 3: deterministic scatter into per-block sub-ranges ----------
__global__ __launch_bounds__(256) void bin_fill(
    const int* __restrict__ eidx, const int* __restrict__ runstart,
    unsigned int* __restrict__ pairs)
{
    __shared__ int lcur[NCB];
    const int blk = blockIdx.x;
    for (int i = threadIdx.x; i < NCB; i += 256) lcur[i] = runstart[blk * NCB + i];
    __syncthreads();
    const int beg = blk * CHUNK;
    const int end = min(beg + CHUNK, N_EDGES);
    for (int e = beg + threadIdx.x; e < end; e += 256) {
        int src = eidx[e];
        int dst = eidx[N_EDGES + e];
        int pos = atomicAdd(&lcur[dst >> 8], 1);
        pairs[pos] = ((unsigned int)src << 8) | (unsigned int)(dst & 255);
    }
}

// ---------- pass 4: fine sort within bucket -> offs[] + csr[] ----------
__global__ __launch_bounds__(256) void fine_sort(
    const unsigned int* __restrict__ pairs,
    const int* __restrict__ boff,
    int* __restrict__ offs,
    int* __restrict__ csr)
{
    __shared__ int cnt[256];
    __shared__ int pfx[256];
    __shared__ int lcur[256];

    const int tid = threadIdx.x;
    const int b   = blockIdx.x;
    const int beg = boff[b];
    const int end = boff[b + 1];

    cnt[tid] = 0;
    __syncthreads();
    for (int j = beg + tid; j < end; j += 256)
        atomicAdd(&cnt[pairs[j] & 255], 1);
    __syncthreads();

    int v = cnt[tid];
    pfx[tid] = v;
    __syncthreads();
    for (int off = 1; off < 256; off <<= 1) {
        int x = (tid >= off) ? pfx[tid - off] : 0;
        __syncthreads();
        pfx[tid] += x;
        __syncthreads();
    }
    int ex = pfx[tid] - v;
    lcur[tid] = ex;
    int gn = b * 256 + tid;
    if (gn < N_NODES) offs[gn] = beg + ex;
    __syncthreads();

    for (int j = beg + tid; j < end; j += 256) {
        unsigned int p = pairs[j];
        int pos = beg + atomicAdd(&lcur[p & 255], 1);
        csr[pos] = (int)(p >> 8);
    }
}

// ---------- fused aggregate + MFMA linear: block = 32 nodes ----------
// Phase A: octet (8 lanes) per node, ushort8 (16B) gathers -> 64 rows in
// flight per wave; mean (bf16) -> LDS. Phase B: 4 waves x 2 MFMA tiles.
#define MROW 72   // means row stride in ushorts (144B, 16B-aligned)
#define S8(j) (((bf2f(v0[j])+bf2f(v1[j]))+(bf2f(v2[j])+bf2f(v3[j]))) \
             + ((bf2f(v4[j])+bf2f(v5[j]))+(bf2f(v6[j])+bf2f(v7[j]))))
#define S4(j) ((bf2f(v0[j])+bf2f(v1[j]))+(bf2f(v2[j])+bf2f(v3[j])))
__global__ __launch_bounds__(256) void agg_gemm(
    const ushort* __restrict__ fb,
    const int* __restrict__ offs,
    const int* __restrict__ csr,
    const ushort* __restrict__ wb,
    const float* __restrict__ bias,
    float* __restrict__ out)
{
    __shared__ __attribute__((aligned(16))) ushort wbl[8192];
    __shared__ __attribute__((aligned(16))) ushort means[32 * MROW];

    const int tid = threadIdx.x;
    const int n0  = blockIdx.x * 32;

    // wb -> LDS (independent of gather; covered by the same barrier)
    {
        const short8v* src = (const short8v*)wb;
        short8v* dst = (short8v*)wbl;
        #pragma unroll
        for (int r = 0; r < 4; ++r) dst[r * 256 + tid] = src[r * 256 + tid];
    }

    // ----- Phase A: gather -----
    const int l    = tid & 7;                 // lane within octet (dims 8l..8l+7)
    const int node = tid >> 3;                // 0..31
    const int n    = n0 + node;

    const int beg = offs[n];
    const int end = offs[n + 1];
    const ushort8v* f8 = (const ushort8v*)fb;   // row stride = 8 ushort8v

    float s0=0.f,s1=0.f,s2=0.f,s3=0.f,s4=0.f,s5=0.f,s6=0.f,s7=0.f;
    int e = beg;
    for (; e + 8 <= end; e += 8) {
        int i0=csr[e+0], i1=csr[e+1], i2=csr[e+2], i3=csr[e+3];
        int i4=csr[e+4], i5=csr[e+5], i6=csr[e+6], i7=csr[e+7];
        ushort8v v0 = f8[(size_t)i0 * 8 + l];
        ushort8v v1 = f8[(size_t)i1 * 8 + l];
        ushort8v v2 = f8[(size_t)i2 * 8 + l];
        ushort8v v3 = f8[(size_t)i3 * 8 + l];
        ushort8v v4 = f8[(size_t)i4 * 8 + l];
        ushort8v v5 = f8[(size_t)i5 * 8 + l];
        ushort8v v6 = f8[(size_t)i6 * 8 + l];
        ushort8v v7 = f8[(size_t)i7 * 8 + l];
        s0 += S8(0); s1 += S8(1); s2 += S8(2); s3 += S8(3);
        s4 += S8(4); s5 += S8(5); s6 += S8(6); s7 += S8(7);
    }
    for (; e + 4 <= end; e += 4) {
        int i0=csr[e+0], i1=csr[e+1], i2=csr[e+2], i3=csr[e+3];
        ushort8v v0 = f8[(size_t)i0 * 8 + l];
        ushort8v v1 = f8[(size_t)i1 * 8 + l];
        ushort8v v2 = f8[(size_t)i2 * 8 + l];
        ushort8v v3 = f8[(size_t)i3 * 8 + l];
        s0 += S4(0); s1 += S4(1); s2 += S4(2); s3 += S4(3);
        s4 += S4(4); s5 += S4(5); s6 += S4(6); s7 += S4(7);
    }
    for (; e < end; ++e) {
        ushort8v v0 = f8[(size_t)csr[e] * 8 + l];
        s0 += bf2f(v0[0]); s1 += bf2f(v0[1]); s2 += bf2f(v0[2]); s3 += bf2f(v0[3]);
        s4 += bf2f(v0[4]); s5 += bf2f(v0[5]); s6 += bf2f(v0[6]); s7 += bf2f(v0[7]);
    }

    float dg = (float)(end - beg);
    dg = dg > 1.0f ? dg : 1.0f;
    float inv = 1.0f / dg;
    {
        ushort8v m;
        m[0]=f2bf(s0*inv); m[1]=f2bf(s1*inv); m[2]=f2bf(s2*inv); m[3]=f2bf(s3*inv);
        m[4]=f2bf(s4*inv); m[5]=f2bf(s5*inv); m[6]=f2bf(s6*inv); m[7]=f2bf(s7*inv);
        *(ushort8v*)(means + node * MROW + l * 8) = m;
    }
    __syncthreads();

    // ----- Phase B: MFMA. wave wv: row-tile rt = wv>>1 (16 nodes), col pair wv&1 -----
    const int lane = tid & 63;
    const int wv   = tid >> 6;
    const int rt   = wv >> 1;
    const int cp   = wv & 1;
    const int kg   = lane >> 4;
    const int cl   = lane & 15;

    const ushort* frow = fb + (size_t)(n0 + rt * 16 + cl) * 64;
    const ushort* mrow = means + (rt * 16 + cl) * MROW;
    short8v a0 = *(const short8v*)(frow + kg * 8);
    short8v a1 = *(const short8v*)(frow + 32 + kg * 8);
    short8v a2 = *(const short8v*)(mrow + kg * 8);
    short8v a3 = *(const short8v*)(mrow + 32 + kg * 8);

    #pragma unroll
    for (int q = 0; q < 2; ++q) {
        const int c4 = cp * 2 + q;
        float bv = bias[c4 * 16 + cl];
        f32x4 acc = (f32x4){bv, bv, bv, bv};
        acc = __builtin_amdgcn_mfma_f32_16x16x32_bf16(
            a0, *(const short8v*)(wbl + (size_t)((0 * 4 + c4) * 64 + lane) * 8), acc, 0, 0, 0);
        acc = __builtin_amdgcn_mfma_f32_16x16x32_bf16(
            a1, *(const short8v*)(wbl + (size_t)((1 * 4 + c4) * 64 + lane) * 8), acc, 0, 0, 0);
        acc = __builtin_amdgcn_mfma_f32_16x16x32_bf16(
            a2, *(const short8v*)(wbl + (size_t)((2 * 4 + c4) * 64 + lane) * 8), acc, 0, 0, 0);
        acc = __builtin_amdgcn_mfma_f32_16x16x32_bf16(
            a3, *(const short8v*)(wbl + (size_t)((3 * 4 + c4) * 64 + lane) * 8), acc, 0, 0, 0);
        #pragma unroll
        for (int r = 0; r < 4; ++r)
            out[(size_t)(n0 + rt * 16 + kg * 4 + r) * 64 + c4 * 16 + cl] = acc[r];
    }
}

extern "C" void kernel_launch(void* const* d_in, const int* in_sizes, int n_in,
                              void* d_out, int out_size, void* d_ws, size_t ws_size,
                              hipStream_t stream) {
    const float* feat = (const float*)d_in[0];
    const int*   eidx = (const int*)d_in[1];
    const float* W    = (const float*)d_in[2];
    const float* bias = (const float*)d_in[3];
    float* out = (float*)d_out;

    // ws layout (~11 MB)
    int* hist     = (int*)d_ws;                        // NBLK*NCB
    int* totP     = hist + NBLK * NCB;                 // NCB*PAD (memset)
    int* runstart = totP + NCB * PAD;                  // NBLK*NCB
    int* boff     = runstart + NBLK * NCB;             // NCB + 2
    int* offs     = boff + NCB + 2;                    // N_NODES + 1
    int* csr      = offs + N_NODES + 1;                // N_EDGES
    ushort* wb    = (ushort*)(csr + N_EDGES);          // 8192 bf16 W frag table
    unsigned int* pairs = (unsigned int*)(wb + 8192);  // N_EDGES
    ushort* fb    = (ushort*)(pairs + N_EDGES);        // N_NODES*D bf16

    hipMemsetAsync(totP, 0, (size_t)NCB * PAD * sizeof(int), stream);

    bin_hist<<<NBLK, 256, 0, stream>>>(eidx, hist, totP, feat, fb, W, wb);
    rstart<<<NCB, 256, 0, stream>>>(totP, hist, boff, runstart, offs);
    bin_fill<<<NBLK, 256, 0, stream>>>(eidx, runstart, pairs);
    fine_sort<<<NCB, 256, 0, stream>>>(pairs, boff, offs, csr);
    agg_gemm<<<N_NODES / 32, 256, 0, stream>>>(fb, offs, csr, wb, bias, out);
}